// Round 1
// baseline (414.811 us; speedup 1.0000x reference)
//
#include <hip/hip_runtime.h>
#include <math.h>

typedef __attribute__((ext_vector_type(8))) short short8;
typedef __attribute__((ext_vector_type(4))) float f32x4;
typedef __attribute__((ext_vector_type(4))) unsigned short us4;
typedef unsigned short u16;
typedef unsigned int u32;

#define LOG2E 1.4426950408889634f
// B=4, S=2048, E=1024, H=16, D=64, M=B*S=8192

static __device__ __forceinline__ u16 f2bf(float f){
  u32 u = __builtin_bit_cast(u32, f);
  u = (u + 0x7FFFu + ((u >> 16) & 1u)) >> 16;   // RTNE
  return (u16)u;
}

static __device__ __forceinline__ void gload16(const void* g, void* l){
  __builtin_amdgcn_global_load_lds((const __attribute__((address_space(1))) void*)g,
                                   (__attribute__((address_space(3))) void*)l,
                                   16, 0, 0);
}

static __device__ __forceinline__ f32x4 mfma16(short8 a, short8 b, f32x4 c){
  return __builtin_amdgcn_mfma_f32_16x16x32_bf16(a, b, c, 0, 0, 0);
}

// ---------------- RoPE cos/sin table: [s][i], i = 0..31 ----------------
__global__ void rope_tab_k(float* __restrict__ cosT, float* __restrict__ sinT){
  int idx = blockIdx.x * 256 + threadIdx.x;   // 2048*32 = 65536
  int s = idx >> 5, i = idx & 31;
  double th = pow(10000.0, -((double)(2 * i)) / 64.0);
  float ang = (float)s * (float)th;           // fp32 rounding matches reference
  cosT[idx] = (float)cos((double)ang);
  sinT[idx] = (float)sin((double)ang);
}

// ---------------- x fp32 -> bf16 ----------------
__global__ void cvt_x_k(const float* __restrict__ x, u16* __restrict__ xb, int n){
  int i = (blockIdx.x * 256 + threadIdx.x) * 4;
  if (i >= n) return;
  f32x4 v = *(const f32x4*)(x + i);
  us4 o; o[0]=f2bf(v[0]); o[1]=f2bf(v[1]); o[2]=f2bf(v[2]); o[3]=f2bf(v[3]);
  *(us4*)(xb + i) = o;
}

// ---------------- W (k,n) fp32 -> WT (n,k) bf16, 4 matrices ----------------
__global__ void wt_cvt_k(const float* __restrict__ W0, const float* __restrict__ W1,
                         const float* __restrict__ W2, const float* __restrict__ W3,
                         u16* __restrict__ out){
  __shared__ float t[32][33];
  const float* W = (blockIdx.z == 0) ? W0 : (blockIdx.z == 1) ? W1 : (blockIdx.z == 2) ? W2 : W3;
  u16* O = out + (size_t)blockIdx.z * 1024 * 1024;
  int tx = threadIdx.x, ty = threadIdx.y;
  int kb = blockIdx.y * 32, nb = blockIdx.x * 32;
  #pragma unroll
  for (int i = 0; i < 4; i++)
    t[ty + i*8][tx] = W[(size_t)(kb + ty + i*8) * 1024 + nb + tx];
  __syncthreads();
  #pragma unroll
  for (int i = 0; i < 4; i++)
    O[(size_t)(nb + ty + i*8) * 1024 + kb + tx] = f2bf(t[tx][ty + i*8]);
}

// ---------------- GEMM 8192x1024x1024 bf16 MFMA, fused epilogues ----------------
// MODE: 0=Q (bias+rope+0.125 -> (b,h,s,d))  1=K (bias+rope -> (b,h,s,d))
//       2=V (bias -> (b,h,d,s))             3=OUT (bias -> fp32 d_out (m,n))
template<int MODE>
__global__ __launch_bounds__(256, 2)
void gemm_ep_k(const u16* __restrict__ A, const u16* __restrict__ BT,
               const float* __restrict__ bias,
               const float* __restrict__ cosT, const float* __restrict__ sinT,
               u16* __restrict__ outB, float* __restrict__ outF)
{
  __shared__ __align__(16) u16 Al[128][64];
  __shared__ __align__(16) u16 Bl[128][64];
  const int tid = threadIdx.x;
  const int w = tid >> 6, lane = tid & 63, g = lane >> 4, c = lane & 15;
  const int wr = w >> 1, wc = w & 1;
  const int R0 = blockIdx.x * 128, C0 = blockIdx.y * 128;

  f32x4 acc[4][4];
  const f32x4 vz = {0.f, 0.f, 0.f, 0.f};
  #pragma unroll
  for (int mi = 0; mi < 4; mi++)
    #pragma unroll
    for (int ni = 0; ni < 4; ni++) acc[mi][ni] = vz;

  const u16* gA[4]; const u16* gB[4]; u16* lA[4]; u16* lB[4];
  #pragma unroll
  for (int i = 0; i < 4; i++){
    int I = w * 4 + i;
    int rr = I * 8 + (lane >> 3), kk = (lane & 7) * 8;
    gA[i] = A  + (size_t)(R0 + rr) * 1024 + kk;
    gB[i] = BT + (size_t)(C0 + rr) * 1024 + kk;
    lA[i] = &Al[I * 8][0];
    lB[i] = &Bl[I * 8][0];
  }

  for (int t = 0; t < 16; ++t){
    const int k0 = t * 64;
    #pragma unroll
    for (int i = 0; i < 4; i++){
      gload16(gA[i] + k0, lA[i]);
      gload16(gB[i] + k0, lB[i]);
    }
    __syncthreads();
    #pragma unroll
    for (int ki = 0; ki < 2; ++ki){
      short8 af[4], bfr[4];
      #pragma unroll
      for (int mi = 0; mi < 4; mi++) af[mi]  = *(const short8*)&Al[wr*64 + mi*16 + c][ki*32 + g*8];
      #pragma unroll
      for (int ni = 0; ni < 4; ni++) bfr[ni] = *(const short8*)&Bl[wc*64 + ni*16 + c][ki*32 + g*8];
      #pragma unroll
      for (int mi = 0; mi < 4; mi++)
        #pragma unroll
        for (int ni = 0; ni < 4; ni++)
          acc[mi][ni] = mfma16(af[mi], bfr[ni], acc[mi][ni]);
    }
    __syncthreads();
  }

  if (MODE == 3){
    #pragma unroll
    for (int mi = 0; mi < 4; mi++){
      #pragma unroll
      for (int ni = 0; ni < 4; ni++){
        int col = C0 + wc*64 + ni*16 + c;
        float bv = bias[col];
        int row0 = R0 + wr*64 + mi*16 + g*4;
        #pragma unroll
        for (int r = 0; r < 4; r++)
          outF[(size_t)(row0 + r) * 1024 + col] = acc[mi][ni][r] + bv;
      }
    }
  } else if (MODE == 2){
    int h = blockIdx.y * 2 + wc;
    #pragma unroll
    for (int ni = 0; ni < 4; ni++){
      int col = C0 + wc*64 + ni*16 + c;
      int d = ni*16 + c;
      float bv = bias[col];
      #pragma unroll
      for (int mi = 0; mi < 4; mi++){
        int row0 = R0 + wr*64 + mi*16 + g*4;
        int b = row0 >> 11, s0 = row0 & 2047;
        us4 pk;
        #pragma unroll
        for (int r = 0; r < 4; r++) pk[r] = f2bf(acc[mi][ni][r] + bv);
        *(us4*)&outB[((size_t)(b*16 + h)*64 + d)*2048 + s0] = pk;
      }
    }
  } else {
    int h = blockIdx.y * 2 + wc;
    float bv[4];
    #pragma unroll
    for (int ni = 0; ni < 4; ni++) bv[ni] = bias[C0 + wc*64 + ni*16 + c];
    #pragma unroll
    for (int mi = 0; mi < 4; mi++){
      int row0 = R0 + wr*64 + mi*16 + g*4;
      int b = row0 >> 11;
      #pragma unroll
      for (int r = 0; r < 4; r++){
        int s = (row0 + r) & 2047;
        float v0 = acc[mi][0][r] + bv[0];
        float v1 = acc[mi][1][r] + bv[1];
        float v2 = acc[mi][2][r] + bv[2];
        float v3 = acc[mi][3][r] + bv[3];
        float ca = cosT[s*32 + c],      sa = sinT[s*32 + c];
        float cb = cosT[s*32 + 16 + c], sb = sinT[s*32 + 16 + c];
        float o0 = v0*ca - v2*sa, o2 = v2*ca + v0*sa;
        float o1 = v1*cb - v3*sb, o3 = v3*cb + v1*sb;
        if (MODE == 0){ o0 *= 0.125f; o1 *= 0.125f; o2 *= 0.125f; o3 *= 0.125f; }
        size_t base = ((size_t)(b*16 + h)*2048 + s)*64;
        outB[base +  0 + c] = f2bf(o0);
        outB[base + 16 + c] = f2bf(o1);
        outB[base + 32 + c] = f2bf(o2);
        outB[base + 48 + c] = f2bf(o3);
      }
    }
  }
}

// ---------------- flash attention ----------------
// Q,K: (b,h,s,d) bf16 (Q pre-scaled by 1/8).  V: (b,h,d,s) bf16.
// out AO: (b,s,h,d) bf16.  Block: 4 waves x 32 q-rows = 128 q-rows. KV tiles of 64.
__global__ __launch_bounds__(256, 2)
void attn_fwd_k(const u16* __restrict__ Q, const u16* __restrict__ K, const u16* __restrict__ V,
                const int* __restrict__ msk, u16* __restrict__ AO)
{
  __shared__ __align__(16) u16 Kl[64][64];        // [t_local][d]
  __shared__ __align__(16) u16 Vl[64][64];        // [d][t_local]
  __shared__ __align__(16) u16 Pl[4][32][64];     // per-wave P transpose buffer
  const int tid = threadIdx.x;
  const int w = tid >> 6, lane = tid & 63, g = lane >> 4, c = lane & 15;
  const int bh = blockIdx.y, b = bh >> 4, h = bh & 15;
  const int qw = blockIdx.x * 128 + w * 32;

  // Q A-fragments (held in registers for the whole block)
  short8 qa[2][2];
  #pragma unroll
  for (int mi = 0; mi < 2; mi++)
    #pragma unroll
    for (int ki = 0; ki < 2; ki++)
      qa[mi][ki] = *(const short8*)&Q[((size_t)bh*2048 + qw + mi*16 + c)*64 + ki*32 + g*8];

  f32x4 oacc[2][4];
  float mrun[2][4], lrun[2][4];
  const f32x4 vz = {0.f, 0.f, 0.f, 0.f};
  #pragma unroll
  for (int mi = 0; mi < 2; mi++){
    #pragma unroll
    for (int nd = 0; nd < 4; nd++) oacc[mi][nd] = vz;
    #pragma unroll
    for (int r = 0; r < 4; r++){ mrun[mi][r] = -1e30f; lrun[mi][r] = 0.f; }
  }

  const u16 *gK[2], *gV[2]; u16 *lK[2], *lV[2];
  #pragma unroll
  for (int i = 0; i < 2; i++){
    int I = w * 2 + i;
    gK[i] = K + ((size_t)bh*2048 + I*8 + (lane >> 3))*64 + (lane & 7)*8;
    gV[i] = V + ((size_t)bh*64   + I*8 + (lane >> 3))*2048 + (lane & 7)*8;
    lK[i] = &Kl[I*8][0];
    lV[i] = &Vl[I*8][0];
  }

  for (int t = 0; t < 32; ++t){
    const int t0 = t * 64;
    #pragma unroll
    for (int i = 0; i < 2; i++){
      gload16(gK[i] + (size_t)t0 * 64, lK[i]);
      gload16(gV[i] + t0, lV[i]);
    }
    __syncthreads();

    // scores = Q @ K^T   (Q pre-scaled by 1/sqrt(D))
    f32x4 sacc[2][4];
    #pragma unroll
    for (int mi = 0; mi < 2; mi++)
      #pragma unroll
      for (int nk = 0; nk < 4; nk++) sacc[mi][nk] = vz;
    #pragma unroll
    for (int ki = 0; ki < 2; ki++){
      short8 kb[4];
      #pragma unroll
      for (int nk = 0; nk < 4; nk++) kb[nk] = *(const short8*)&Kl[nk*16 + c][ki*32 + g*8];
      #pragma unroll
      for (int mi = 0; mi < 2; mi++)
        #pragma unroll
        for (int nk = 0; nk < 4; nk++)
          sacc[mi][nk] = mfma16(qa[mi][ki], kb[nk], sacc[mi][nk]);
    }

    // mask (attn_mask[b][t]==0 -> -1e9)
    int mv[4];
    #pragma unroll
    for (int nk = 0; nk < 4; nk++) mv[nk] = msk[b*2048 + t0 + nk*16 + c];
    #pragma unroll
    for (int mi = 0; mi < 2; mi++)
      #pragma unroll
      for (int nk = 0; nk < 4; nk++)
        if (mv[nk] == 0){
          #pragma unroll
          for (int r = 0; r < 4; r++) sacc[mi][nk][r] = -1e9f;
        }

    // online softmax (rows: mi*16+g*4+r; cols across 16 c-lanes x 4 nk-frags)
    float mnew[2][4], alpha[2][4];
    #pragma unroll
    for (int mi = 0; mi < 2; mi++)
      #pragma unroll
      for (int r = 0; r < 4; r++){
        float pm = fmaxf(fmaxf(sacc[mi][0][r], sacc[mi][1][r]),
                         fmaxf(sacc[mi][2][r], sacc[mi][3][r]));
        #pragma unroll
        for (int sft = 1; sft < 16; sft <<= 1) pm = fmaxf(pm, __shfl_xor(pm, sft, 64));
        float mn = fmaxf(mrun[mi][r], pm);
        mnew[mi][r] = mn;
        alpha[mi][r] = exp2f((mrun[mi][r] - mn) * LOG2E);
      }

    float rs[2][4];
    #pragma unroll
    for (int mi = 0; mi < 2; mi++)
      #pragma unroll
      for (int r = 0; r < 4; r++) rs[mi][r] = 0.f;
    #pragma unroll
    for (int mi = 0; mi < 2; mi++)
      #pragma unroll
      for (int nk = 0; nk < 4; nk++)
        #pragma unroll
        for (int r = 0; r < 4; r++){
          float p = exp2f((sacc[mi][nk][r] - mnew[mi][r]) * LOG2E);
          rs[mi][r] += p;
          Pl[w][mi*16 + g*4 + r][nk*16 + c] = f2bf(p);   // C-layout -> LDS
        }
    #pragma unroll
    for (int mi = 0; mi < 2; mi++)
      #pragma unroll
      for (int r = 0; r < 4; r++){
        float sm = rs[mi][r];
        #pragma unroll
        for (int sft = 1; sft < 16; sft <<= 1) sm += __shfl_xor(sm, sft, 64);
        lrun[mi][r] = lrun[mi][r] * alpha[mi][r] + sm;
        mrun[mi][r] = mnew[mi][r];
      }
    #pragma unroll
    for (int mi = 0; mi < 2; mi++)
      #pragma unroll
      for (int nd = 0; nd < 4; nd++)
        #pragma unroll
        for (int r = 0; r < 4; r++) oacc[mi][nd][r] *= alpha[mi][r];

    // wave-private LDS: ensure P writes land before A-layout reads
    asm volatile("s_waitcnt lgkmcnt(0)" ::: "memory");

    short8 pa[2][2];
    #pragma unroll
    for (int mi = 0; mi < 2; mi++)
      #pragma unroll
      for (int ki = 0; ki < 2; ki++)
        pa[mi][ki] = *(const short8*)&Pl[w][mi*16 + c][ki*32 + g*8];

    #pragma unroll
    for (int ki = 0; ki < 2; ki++){
      short8 vb[4];
      #pragma unroll
      for (int nd = 0; nd < 4; nd++) vb[nd] = *(const short8*)&Vl[nd*16 + c][ki*32 + g*8];
      #pragma unroll
      for (int mi = 0; mi < 2; mi++)
        #pragma unroll
        for (int nd = 0; nd < 4; nd++)
          oacc[mi][nd] = mfma16(pa[mi][ki], vb[nd], oacc[mi][nd]);
    }
    __syncthreads();
  }

  // epilogue: normalize, write AO (b,s,h,d)
  #pragma unroll
  for (int mi = 0; mi < 2; mi++){
    #pragma unroll
    for (int r = 0; r < 4; r++){
      int s = qw + mi*16 + g*4 + r;
      float inv = 1.0f / lrun[mi][r];
      size_t base = ((size_t)b*2048 + s)*1024 + h*64;
      #pragma unroll
      for (int nd = 0; nd < 4; nd++)
        AO[base + nd*16 + c] = f2bf(oacc[mi][nd][r] * inv);
    }
  }
}

extern "C" void kernel_launch(void* const* d_in, const int* in_sizes, int n_in,
                              void* d_out, int out_size, void* d_ws, size_t ws_size,
                              hipStream_t stream)
{
  const float* x  = (const float*)d_in[0];
  const int* mask = (const int*)d_in[1];
  const float* Wq = (const float*)d_in[2];
  const float* bq = (const float*)d_in[3];
  const float* Wk = (const float*)d_in[4];
  const float* bk = (const float*)d_in[5];
  const float* Wv = (const float*)d_in[6];
  const float* bv = (const float*)d_in[7];
  const float* Wo = (const float*)d_in[8];
  const float* bo = (const float*)d_in[9];
  float* out = (float*)d_out;
  (void)in_sizes; (void)n_in; (void)out_size; (void)ws_size;

  char* ws = (char*)d_ws;
  size_t off = 0;
  auto alloc = [&](size_t bytes){ void* p = ws + off; off += (bytes + 255) & ~(size_t)255; return p; };
  u16* xb    = (u16*)alloc((size_t)8192 * 1024 * 2);
  u16* WT    = (u16*)alloc((size_t)4 * 1024 * 1024 * 2);
  float* cosT = (float*)alloc((size_t)2048 * 32 * 4);
  float* sinT = (float*)alloc((size_t)2048 * 32 * 4);
  u16* Qr    = (u16*)alloc((size_t)8192 * 1024 * 2);
  u16* Kr    = (u16*)alloc((size_t)8192 * 1024 * 2);
  u16* Vt    = (u16*)alloc((size_t)8192 * 1024 * 2);
  u16* AO    = (u16*)alloc((size_t)8192 * 1024 * 2);

  rope_tab_k<<<dim3(256), dim3(256), 0, stream>>>(cosT, sinT);
  cvt_x_k<<<dim3(8192), dim3(256), 0, stream>>>(x, xb, 8192 * 1024);
  wt_cvt_k<<<dim3(32, 32, 4), dim3(32, 8), 0, stream>>>(Wq, Wk, Wv, Wo, WT);

  dim3 gg(64, 8), gb(256);
  gemm_ep_k<0><<<gg, gb, 0, stream>>>(xb, WT + 0*1024*1024, bq, cosT, sinT, Qr, nullptr);
  gemm_ep_k<1><<<gg, gb, 0, stream>>>(xb, WT + 1*1024*1024, bk, cosT, sinT, Kr, nullptr);
  gemm_ep_k<2><<<gg, gb, 0, stream>>>(xb, WT + 2*1024*1024, bv, cosT, sinT, Vt, nullptr);

  attn_fwd_k<<<dim3(16, 64), dim3(256), 0, stream>>>(Qr, Kr, Vt, mask, AO);

  gemm_ep_k<3><<<gg, gb, 0, stream>>>(AO, WT + 3*1024*1024, bo, cosT, sinT, nullptr, out);
}

// Round 3
// 313.575 us; speedup vs baseline: 1.3228x; 1.3228x over previous
//
#include <hip/hip_runtime.h>
#include <math.h>

typedef __attribute__((ext_vector_type(8))) short short8;
typedef __attribute__((ext_vector_type(4))) float f32x4;
typedef __attribute__((ext_vector_type(4))) unsigned short us4;
typedef __attribute__((ext_vector_type(4))) unsigned int u32x4;
typedef __attribute__((ext_vector_type(4))) int i32x4;
typedef unsigned short u16;
typedef unsigned int u32;

#define LOG2E 1.4426950408889634f
// B=4, S=2048, E=1024, H=16, D=64, M=B*S=8192

static __device__ __forceinline__ u16 f2bf(float f){
  u32 u = __builtin_bit_cast(u32, f);
  u = (u + 0x7FFFu + ((u >> 16) & 1u)) >> 16;   // RTNE
  return (u16)u;
}

static __device__ __forceinline__ void gload16(const void* g, void* l){
  __builtin_amdgcn_global_load_lds((const __attribute__((address_space(1))) void*)g,
                                   (__attribute__((address_space(3))) void*)l,
                                   16, 0, 0);
}

static __device__ __forceinline__ f32x4 mfma16(short8 a, short8 b, f32x4 c){
  return __builtin_amdgcn_mfma_f32_16x16x32_bf16(a, b, c, 0, 0, 0);
}

// ---------------- RoPE cos/sin table: [s][i], i = 0..31 ----------------
__global__ void rope_tab_k(float* __restrict__ cosT, float* __restrict__ sinT){
  int idx = blockIdx.x * 256 + threadIdx.x;   // 2048*32 = 65536
  int s = idx >> 5, i = idx & 31;
  double th = pow(10000.0, -((double)(2 * i)) / 64.0);
  float ang = (float)s * (float)th;           // fp32 rounding matches reference
  cosT[idx] = (float)cos((double)ang);
  sinT[idx] = (float)sin((double)ang);
}

// ---------------- x fp32 -> bf16 ----------------
__global__ void cvt_x_k(const float* __restrict__ x, u16* __restrict__ xb, int n){
  int i = (blockIdx.x * 256 + threadIdx.x) * 4;
  if (i >= n) return;
  f32x4 v = *(const f32x4*)(x + i);
  us4 o; o[0]=f2bf(v[0]); o[1]=f2bf(v[1]); o[2]=f2bf(v[2]); o[3]=f2bf(v[3]);
  *(us4*)(xb + i) = o;
}

// ---------------- W (k,n) fp32 -> WT (n,k) bf16, 4 matrices ----------------
__global__ void wt_cvt_k(const float* __restrict__ W0, const float* __restrict__ W1,
                         const float* __restrict__ W2, const float* __restrict__ W3,
                         u16* __restrict__ out){
  __shared__ float t[32][33];
  const float* W = (blockIdx.z == 0) ? W0 : (blockIdx.z == 1) ? W1 : (blockIdx.z == 2) ? W2 : W3;
  u16* O = out + (size_t)blockIdx.z * 1024 * 1024;
  int tx = threadIdx.x, ty = threadIdx.y;
  int kb = blockIdx.y * 32, nb = blockIdx.x * 32;
  #pragma unroll
  for (int i = 0; i < 4; i++)
    t[ty + i*8][tx] = W[(size_t)(kb + ty + i*8) * 1024 + nb + tx];
  __syncthreads();
  #pragma unroll
  for (int i = 0; i < 4; i++)
    O[(size_t)(nb + ty + i*8) * 1024 + kb + tx] = f2bf(t[tx][ty + i*8]);
}

// ---------------- GEMM 8192x1024x1024 bf16 MFMA, fused epilogues ----------------
// MODE: 0=Q (bias+rope+0.125 -> (b,h,s,d))  1=K (bias+rope -> (b,h,s,d))
//       2=V (bias -> (b,h,d,s))             3=OUT (bias -> fp32 d_out (m,n))
template<int MODE>
__global__ __launch_bounds__(256, 2)
void gemm_ep_k(const u16* __restrict__ A, const u16* __restrict__ BT,
               const float* __restrict__ bias,
               const float* __restrict__ cosT, const float* __restrict__ sinT,
               u16* __restrict__ outB, float* __restrict__ outF)
{
  __shared__ __align__(16) u16 Al[128][64];
  __shared__ __align__(16) u16 Bl[128][64];
  const int tid = threadIdx.x;
  const int w = tid >> 6, lane = tid & 63, g = lane >> 4, c = lane & 15;
  const int wr = w >> 1, wc = w & 1;
  const int R0 = blockIdx.x * 128, C0 = blockIdx.y * 128;

  f32x4 acc[4][4];
  const f32x4 vz = {0.f, 0.f, 0.f, 0.f};
  #pragma unroll
  for (int mi = 0; mi < 4; mi++)
    #pragma unroll
    for (int ni = 0; ni < 4; ni++) acc[mi][ni] = vz;

  const u16* gA[4]; const u16* gB[4]; u16* lA[4]; u16* lB[4];
  #pragma unroll
  for (int i = 0; i < 4; i++){
    int I = w * 4 + i;
    int rr = I * 8 + (lane >> 3), kk = (lane & 7) * 8;
    gA[i] = A  + (size_t)(R0 + rr) * 1024 + kk;
    gB[i] = BT + (size_t)(C0 + rr) * 1024 + kk;
    lA[i] = &Al[I * 8][0];
    lB[i] = &Bl[I * 8][0];
  }

  for (int t = 0; t < 16; ++t){
    const int k0 = t * 64;
    #pragma unroll
    for (int i = 0; i < 4; i++){
      gload16(gA[i] + k0, lA[i]);
      gload16(gB[i] + k0, lB[i]);
    }
    __syncthreads();
    #pragma unroll
    for (int ki = 0; ki < 2; ++ki){
      short8 af[4], bfr[4];
      #pragma unroll
      for (int mi = 0; mi < 4; mi++) af[mi]  = *(const short8*)&Al[wr*64 + mi*16 + c][ki*32 + g*8];
      #pragma unroll
      for (int ni = 0; ni < 4; ni++) bfr[ni] = *(const short8*)&Bl[wc*64 + ni*16 + c][ki*32 + g*8];
      #pragma unroll
      for (int mi = 0; mi < 4; mi++)
        #pragma unroll
        for (int ni = 0; ni < 4; ni++)
          acc[mi][ni] = mfma16(af[mi], bfr[ni], acc[mi][ni]);
    }
    __syncthreads();
  }

  if (MODE == 3){
    #pragma unroll
    for (int mi = 0; mi < 4; mi++){
      #pragma unroll
      for (int ni = 0; ni < 4; ni++){
        int col = C0 + wc*64 + ni*16 + c;
        float bv = bias[col];
        int row0 = R0 + wr*64 + mi*16 + g*4;
        #pragma unroll
        for (int r = 0; r < 4; r++)
          outF[(size_t)(row0 + r) * 1024 + col] = acc[mi][ni][r] + bv;
      }
    }
  } else if (MODE == 2){
    int h = blockIdx.y * 2 + wc;
    #pragma unroll
    for (int ni = 0; ni < 4; ni++){
      int col = C0 + wc*64 + ni*16 + c;
      int d = ni*16 + c;
      float bv = bias[col];
      #pragma unroll
      for (int mi = 0; mi < 4; mi++){
        int row0 = R0 + wr*64 + mi*16 + g*4;
        int b = row0 >> 11, s0 = row0 & 2047;
        us4 pk;
        #pragma unroll
        for (int r = 0; r < 4; r++) pk[r] = f2bf(acc[mi][ni][r] + bv);
        *(us4*)&outB[((size_t)(b*16 + h)*64 + d)*2048 + s0] = pk;
      }
    }
  } else {
    int h = blockIdx.y * 2 + wc;
    float bv[4];
    #pragma unroll
    for (int ni = 0; ni < 4; ni++) bv[ni] = bias[C0 + wc*64 + ni*16 + c];
    #pragma unroll
    for (int mi = 0; mi < 4; mi++){
      int row0 = R0 + wr*64 + mi*16 + g*4;
      int b = row0 >> 11;
      #pragma unroll
      for (int r = 0; r < 4; r++){
        int s = (row0 + r) & 2047;
        float v0 = acc[mi][0][r] + bv[0];
        float v1 = acc[mi][1][r] + bv[1];
        float v2 = acc[mi][2][r] + bv[2];
        float v3 = acc[mi][3][r] + bv[3];
        float ca = cosT[s*32 + c],      sa = sinT[s*32 + c];
        float cb = cosT[s*32 + 16 + c], sb = sinT[s*32 + 16 + c];
        float o0 = v0*ca - v2*sa, o2 = v2*ca + v0*sa;
        float o1 = v1*cb - v3*sb, o3 = v3*cb + v1*sb;
        if (MODE == 0){ o0 *= 0.125f; o1 *= 0.125f; o2 *= 0.125f; o3 *= 0.125f; }
        size_t base = ((size_t)(b*16 + h)*2048 + s)*64;
        outB[base +  0 + c] = f2bf(o0);
        outB[base + 16 + c] = f2bf(o1);
        outB[base + 32 + c] = f2bf(o2);
        outB[base + 48 + c] = f2bf(o3);
      }
    }
  }
}

// ---------------- flash attention (swapped-QK^T, zero-shuffle PV) ----------------
// Q,K: (b,h,s,d) bf16 (Q pre-scaled by 0.125).  V: (b,h,d,s) bf16.
// out AO: (b,s,h,d) bf16.  4 waves x 32 q-rows. KV tiles of 64, double-buffered.
// K rows staged permuted: stored row s holds logical row pi(s) so that the
// S^T C-layout registers, packed pairwise to bf16, ARE the PV A-fragment.
// K/V LDS cols XOR-swizzled (pre-swizzled global source) -> conflict-free b128.
// P->bf16 via RTNE f2bf; softmax denominator summed from the ROUNDED p values
// so numerator/denominator rounding bias cancels in P*V/L.
__global__ __launch_bounds__(256, 4)
void attn_fwd_k(const u16* __restrict__ Q, const u16* __restrict__ K, const u16* __restrict__ V,
                const int* __restrict__ msk, u16* __restrict__ AO)
{
  __shared__ __align__(16) u16 Kl[2][64][64];
  __shared__ __align__(16) u16 Vl[2][64][64];
  __shared__ int Ml[2048];
  const int tid = threadIdx.x;
  const int w = tid >> 6, lane = tid & 63, g = lane >> 4, c = lane & 15;
  const int bh = blockIdx.y, b = bh >> 4, h = bh & 15;
  const int qw = blockIdx.x * 128 + w * 32;

  // per-lane staging sources (pre-swizzled cols; K rows pi-permuted)
  const int l3 = lane >> 3, l7 = lane & 7;
  const int scol = (l7 ^ l3) * 8;
  const u16* gK[2]; const u16* gV[2];
  #pragma unroll
  for (int i = 0; i < 2; i++){
    int s = (w*2 + i)*8 + l3;                                        // stored row
    int ps = (s & 0x20) | ((s & 0x10) >> 2) | ((s & 0x0C) << 1) | (s & 3); // pi(s)
    gK[i] = K + ((size_t)bh*2048 + ps)*64 + scol;
    gV[i] = V + ((size_t)bh*64 + s)*2048 + scol;
  }

  // stage mask row for this b (8KB) into LDS
  {
    const int* ms = msk + b*2048 + w*512 + lane*4;
    gload16(ms,       &Ml[w*512]);
    gload16(ms + 256, &Ml[w*512 + 256]);
  }
  // stage tile 0 into buf 0
  #pragma unroll
  for (int i = 0; i < 2; i++){
    gload16(gK[i], &Kl[0][(w*2+i)*8][0]);
    gload16(gV[i], &Vl[0][(w*2+i)*8][0]);
  }

  // Q B-fragments (row q = qw + mq*16 + c, k-slice ki*32 + g*8)
  short8 qb[2][2];
  #pragma unroll
  for (int mq = 0; mq < 2; mq++)
    #pragma unroll
    for (int ki = 0; ki < 2; ki++)
      qb[mq][ki] = *(const short8*)&Q[((size_t)bh*2048 + qw + mq*16 + c)*64 + ki*32 + g*8];

  f32x4 oacc[2][4];
  float mrun[2], lrun[2];
  const f32x4 vz = {0.f, 0.f, 0.f, 0.f};
  #pragma unroll
  for (int mq = 0; mq < 2; mq++){
    #pragma unroll
    for (int nd = 0; nd < 4; nd++) oacc[mq][nd] = vz;
    mrun[mq] = -1e30f; lrun[mq] = 0.f;
  }

  const int cs0 = (g*8) ^ ((c & 7) << 3);          // swizzled read col, ki=0
  const int cs1 = (32 + g*8) ^ ((c & 7) << 3);     // swizzled read col, ki=1

  for (int t = 0; t < 32; ++t){
    // stage tile t+1 into buf (t+1)&1  (t=31 over-stage is harmless, in-ws)
    {
      const size_t ko = (size_t)(t+1) * 64 * 64;   // u16: 64 rows ahead
      const size_t vo = (size_t)(t+1) * 64;        // u16: 64 cols ahead
      #pragma unroll
      for (int i = 0; i < 2; i++){
        gload16(gK[i] + ko, &Kl[(t+1)&1][(w*2+i)*8][0]);
        gload16(gV[i] + vo, &Vl[(t+1)&1][(w*2+i)*8][0]);
      }
    }
    asm volatile("s_waitcnt vmcnt(4)" ::: "memory");  // tile t drained; t+1 in flight
    __builtin_amdgcn_s_barrier();
    asm volatile("" ::: "memory");

    const u16* Kb = &Kl[t&1][0][0];
    const u16* Vb = &Vl[t&1][0][0];
    const int t0 = t * 64;

    // S^T = K (A) x Q (B): sacc[nt][mq] holds S[q=qw+mq*16+c][stored t = t0+nt*16+4g+r]
    f32x4 sacc[4][2];
    #pragma unroll
    for (int nt = 0; nt < 4; nt++){ sacc[nt][0] = vz; sacc[nt][1] = vz; }
    #pragma unroll
    for (int ki = 0; ki < 2; ki++){
      const int cs = ki ? cs1 : cs0;
      short8 ka[4];
      #pragma unroll
      for (int nt = 0; nt < 4; nt++) ka[nt] = *(const short8*)&Kb[(nt*16 + c)*64 + cs];
      #pragma unroll
      for (int nt = 0; nt < 4; nt++)
        #pragma unroll
        for (int mq = 0; mq < 2; mq++)
          sacc[nt][mq] = mfma16(ka[nt], qb[mq][ki], sacc[nt][mq]);
    }

    // mask: logical t of (nt,g,r) = t0 + 32*(nt>>1) + 8g + 4*(nt&1) + r
    i32x4 mv[4];
    #pragma unroll
    for (int nt = 0; nt < 4; nt++)
      mv[nt] = *(const i32x4*)&Ml[t0 + 32*(nt>>1) + 8*g + 4*(nt&1)];
    #pragma unroll
    for (int nt = 0; nt < 4; nt++)
      #pragma unroll
      for (int r = 0; r < 4; r++){
        if (mv[nt][r] == 0){ sacc[nt][0][r] = -1e9f; sacc[nt][1][r] = -1e9f; }
      }

    // online softmax (natural-domain scores), per lane for q = qw + mq*16 + c
    float al[2];
    short8 pa[2][2];
    #pragma unroll
    for (int mq = 0; mq < 2; mq++){
      float m16 = sacc[0][mq][0];
      #pragma unroll
      for (int nt = 0; nt < 4; nt++)
        #pragma unroll
        for (int r = 0; r < 4; r++)
          m16 = fmaxf(m16, sacc[nt][mq][r]);
      m16 = fmaxf(m16, __shfl_xor(m16, 16, 64));
      m16 = fmaxf(m16, __shfl_xor(m16, 32, 64));
      float mn = fmaxf(mrun[mq], m16);
      al[mq] = exp2f((mrun[mq] - mn) * LOG2E);
      mrun[mq] = mn;
      const float nm = -mn * LOG2E;
      u32 prB[4][4];                     // rounded p as f32 bits (low16 = 0)
      float sum = 0.f;
      #pragma unroll
      for (int nt = 0; nt < 4; nt++)
        #pragma unroll
        for (int r = 0; r < 4; r++){
          float p = exp2f(fmaf(sacc[nt][mq][r], LOG2E, nm));
          u32 pb = (u32)f2bf(p) << 16;   // RTNE bf16, back as f32 bits
          prB[nt][r] = pb;
          sum += __builtin_bit_cast(float, pb);   // denominator == Σ rounded p
        }
      sum += __shfl_xor(sum, 16, 64);
      sum += __shfl_xor(sum, 32, 64);
      lrun[mq] = lrun[mq] * al[mq] + sum;
      #pragma unroll
      for (int ki = 0; ki < 2; ki++){
        u32x4 pk;
        pk[0] = (prB[2*ki  ][0] >> 16) | prB[2*ki  ][1];
        pk[1] = (prB[2*ki  ][2] >> 16) | prB[2*ki  ][3];
        pk[2] = (prB[2*ki+1][0] >> 16) | prB[2*ki+1][1];
        pk[3] = (prB[2*ki+1][2] >> 16) | prB[2*ki+1][3];
        pa[mq][ki] = __builtin_bit_cast(short8, pk);
      }
    }

    // rescale O by alpha (redistribute: O rows are q = 4g+r, alpha lives at q=c)
    #pragma unroll
    for (int mq = 0; mq < 2; mq++){
      float a0 = __shfl(al[mq], g*4 + 0, 64);
      float a1 = __shfl(al[mq], g*4 + 1, 64);
      float a2 = __shfl(al[mq], g*4 + 2, 64);
      float a3 = __shfl(al[mq], g*4 + 3, 64);
      #pragma unroll
      for (int nd = 0; nd < 4; nd++){
        oacc[mq][nd][0] *= a0; oacc[mq][nd][1] *= a1;
        oacc[mq][nd][2] *= a2; oacc[mq][nd][3] *= a3;
      }
    }

    // O += P (A) x V (B)
    #pragma unroll
    for (int ki = 0; ki < 2; ki++){
      const int cs = ki ? cs1 : cs0;
      short8 va[4];
      #pragma unroll
      for (int nd = 0; nd < 4; nd++) va[nd] = *(const short8*)&Vb[(nd*16 + c)*64 + cs];
      #pragma unroll
      for (int mq = 0; mq < 2; mq++)
        #pragma unroll
        for (int nd = 0; nd < 4; nd++)
          oacc[mq][nd] = mfma16(pa[mq][ki], va[nd], oacc[mq][nd]);
    }

    asm volatile("" ::: "memory");
    __builtin_amdgcn_s_barrier();
    asm volatile("" ::: "memory");
  }

  // epilogue: O rows q = qw + mq*16 + 4g + r; l lives at q=c lanes -> shfl
  #pragma unroll
  for (int mq = 0; mq < 2; mq++){
    #pragma unroll
    for (int r = 0; r < 4; r++){
      float li = __shfl(lrun[mq], g*4 + r, 64);
      float inv = 1.0f / li;
      int q = qw + mq*16 + g*4 + r;
      size_t base = ((size_t)b*2048 + q)*1024 + h*64;
      #pragma unroll
      for (int nd = 0; nd < 4; nd++)
        AO[base + nd*16 + c] = f2bf(oacc[mq][nd][r] * inv);
    }
  }
}

extern "C" void kernel_launch(void* const* d_in, const int* in_sizes, int n_in,
                              void* d_out, int out_size, void* d_ws, size_t ws_size,
                              hipStream_t stream)
{
  const float* x  = (const float*)d_in[0];
  const int* mask = (const int*)d_in[1];
  const float* Wq = (const float*)d_in[2];
  const float* bq = (const float*)d_in[3];
  const float* Wk = (const float*)d_in[4];
  const float* bk = (const float*)d_in[5];
  const float* Wv = (const float*)d_in[6];
  const float* bv = (const float*)d_in[7];
  const float* Wo = (const float*)d_in[8];
  const float* bo = (const float*)d_in[9];
  float* out = (float*)d_out;
  (void)in_sizes; (void)n_in; (void)out_size; (void)ws_size;

  char* ws = (char*)d_ws;
  size_t off = 0;
  auto alloc = [&](size_t bytes){ void* p = ws + off; off += (bytes + 255) & ~(size_t)255; return p; };
  u16* xb    = (u16*)alloc((size_t)8192 * 1024 * 2);
  u16* WT    = (u16*)alloc((size_t)4 * 1024 * 1024 * 2);
  float* cosT = (float*)alloc((size_t)2048 * 32 * 4);
  float* sinT = (float*)alloc((size_t)2048 * 32 * 4);
  u16* Qr    = (u16*)alloc((size_t)8192 * 1024 * 2);
  u16* Kr    = (u16*)alloc((size_t)8192 * 1024 * 2);
  u16* Vt    = (u16*)alloc((size_t)8192 * 1024 * 2);
  u16* AO    = (u16*)alloc((size_t)8192 * 1024 * 2);

  rope_tab_k<<<dim3(256), dim3(256), 0, stream>>>(cosT, sinT);
  cvt_x_k<<<dim3(8192), dim3(256), 0, stream>>>(x, xb, 8192 * 1024);
  wt_cvt_k<<<dim3(32, 32, 4), dim3(32, 8), 0, stream>>>(Wq, Wk, Wv, Wo, WT);

  dim3 gg(64, 8), gb(256);
  gemm_ep_k<0><<<gg, gb, 0, stream>>>(xb, WT + 0*1024*1024, bq, cosT, sinT, Qr, nullptr);
  gemm_ep_k<1><<<gg, gb, 0, stream>>>(xb, WT + 1*1024*1024, bk, cosT, sinT, Kr, nullptr);
  gemm_ep_k<2><<<gg, gb, 0, stream>>>(xb, WT + 2*1024*1024, bv, cosT, sinT, Vt, nullptr);

  attn_fwd_k<<<dim3(16, 64), dim3(256), 0, stream>>>(Qr, Kr, Vt, mask, AO);

  gemm_ep_k<3><<<gg, gb, 0, stream>>>(AO, WT + 3*1024*1024, bo, cosT, sinT, nullptr, out);
}

// Round 6
// 264.192 us; speedup vs baseline: 1.5701x; 1.1869x over previous
//
#include <hip/hip_runtime.h>
#include <math.h>

typedef __attribute__((ext_vector_type(8))) short short8;
typedef __attribute__((ext_vector_type(4))) float f32x4;
typedef __attribute__((ext_vector_type(4))) unsigned short us4;
typedef __attribute__((ext_vector_type(4))) unsigned int u32x4;
typedef __attribute__((ext_vector_type(4))) int i32x4;
typedef unsigned short u16;
typedef unsigned int u32;

#define LOG2E 1.4426950408889634f
// B=4, S=2048, E=1024, H=16, D=64, M=B*S=8192

static __device__ __forceinline__ u16 f2bf(float f){
  u32 u = __builtin_bit_cast(u32, f);
  u = (u + 0x7FFFu + ((u >> 16) & 1u)) >> 16;   // RTNE
  return (u16)u;
}
// NOTE: v_cvt_pk_bf16_f32 (and __float22bfloat162_rn) is NOT RTNE on gfx950 —
// using it for the P-pack cost 7e-3 absmax (rounds 2 & 5). Keep manual RTNE.

static __device__ __forceinline__ void gload16(const void* g, void* l){
  __builtin_amdgcn_global_load_lds((const __attribute__((address_space(1))) void*)g,
                                   (__attribute__((address_space(3))) void*)l,
                                   16, 0, 0);
}

static __device__ __forceinline__ f32x4 mfma16(short8 a, short8 b, f32x4 c){
  return __builtin_amdgcn_mfma_f32_16x16x32_bf16(a, b, c, 0, 0, 0);
}

// ---------------- RoPE cos/sin table: [s][i], i = 0..31 ----------------
__global__ void rope_tab_k(float* __restrict__ cosT, float* __restrict__ sinT){
  int idx = blockIdx.x * 256 + threadIdx.x;   // 2048*32 = 65536
  int s = idx >> 5, i = idx & 31;
  double th = pow(10000.0, -((double)(2 * i)) / 64.0);
  float ang = (float)s * (float)th;           // fp32 rounding matches reference
  cosT[idx] = (float)cos((double)ang);
  sinT[idx] = (float)sin((double)ang);
}

// ---------------- x fp32 -> bf16 ----------------
__global__ void cvt_x_k(const float* __restrict__ x, u16* __restrict__ xb, int n){
  int i = (blockIdx.x * 256 + threadIdx.x) * 4;
  if (i >= n) return;
  f32x4 v = *(const f32x4*)(x + i);
  us4 o; o[0]=f2bf(v[0]); o[1]=f2bf(v[1]); o[2]=f2bf(v[2]); o[3]=f2bf(v[3]);
  *(us4*)(xb + i) = o;
}

// ---------------- W (k,n) fp32 -> WT (n,k) bf16, 4 matrices ----------------
__global__ void wt_cvt_k(const float* __restrict__ W0, const float* __restrict__ W1,
                         const float* __restrict__ W2, const float* __restrict__ W3,
                         u16* __restrict__ out){
  __shared__ float t[32][33];
  const float* W = (blockIdx.z == 0) ? W0 : (blockIdx.z == 1) ? W1 : (blockIdx.z == 2) ? W2 : W3;
  u16* O = out + (size_t)blockIdx.z * 1024 * 1024;
  int tx = threadIdx.x, ty = threadIdx.y;
  int kb = blockIdx.y * 32, nb = blockIdx.x * 32;
  #pragma unroll
  for (int i = 0; i < 4; i++)
    t[ty + i*8][tx] = W[(size_t)(kb + ty + i*8) * 1024 + nb + tx];
  __syncthreads();
  #pragma unroll
  for (int i = 0; i < 4; i++)
    O[(size_t)(nb + ty + i*8) * 1024 + kb + tx] = f2bf(t[tx][ty + i*8]);
}

// ---------------- fused QKV GEMM 8192x1024x1024 bf16 MFMA ----------------
// grid (64, 24): mode = y>>3 (0=Q,1=K,2=V), cy = y&7.
// mode 0: bias+rope+0.125 -> Qr (b,h,s,d);  mode 1: bias+rope -> Kr (b,h,s,d)
// mode 2: bias -> Vt (b,h,d,s)
__global__ __launch_bounds__(256, 2)
void qkv_gemm_k(const u16* __restrict__ A, const u16* __restrict__ WT,
                const float* __restrict__ bq, const float* __restrict__ bk,
                const float* __restrict__ bv,
                const float* __restrict__ cosT, const float* __restrict__ sinT,
                u16* __restrict__ Qr, u16* __restrict__ Kr, u16* __restrict__ Vt)
{
  __shared__ __align__(16) u16 Al[128][64];
  __shared__ __align__(16) u16 Bl[128][64];
  const int mode = blockIdx.y >> 3;
  const int cy   = blockIdx.y & 7;
  const u16* BT = WT + (size_t)mode * 1024 * 1024;
  const float* bias = (mode == 0) ? bq : (mode == 1) ? bk : bv;
  u16* outB = (mode == 0) ? Qr : (mode == 1) ? Kr : Vt;

  const int tid = threadIdx.x;
  const int w = tid >> 6, lane = tid & 63, g = lane >> 4, c = lane & 15;
  const int wr = w >> 1, wc = w & 1;
  const int R0 = blockIdx.x * 128, C0 = cy * 128;

  f32x4 acc[4][4];
  const f32x4 vz = {0.f, 0.f, 0.f, 0.f};
  #pragma unroll
  for (int mi = 0; mi < 4; mi++)
    #pragma unroll
    for (int ni = 0; ni < 4; ni++) acc[mi][ni] = vz;

  const u16* gA[4]; const u16* gB[4]; u16* lA[4]; u16* lB[4];
  #pragma unroll
  for (int i = 0; i < 4; i++){
    int I = w * 4 + i;
    int rr = I * 8 + (lane >> 3), kk = (lane & 7) * 8;
    gA[i] = A  + (size_t)(R0 + rr) * 1024 + kk;
    gB[i] = BT + (size_t)(C0 + rr) * 1024 + kk;
    lA[i] = &Al[I * 8][0];
    lB[i] = &Bl[I * 8][0];
  }

  for (int t = 0; t < 16; ++t){
    const int k0 = t * 64;
    #pragma unroll
    for (int i = 0; i < 4; i++){
      gload16(gA[i] + k0, lA[i]);
      gload16(gB[i] + k0, lB[i]);
    }
    __syncthreads();
    #pragma unroll
    for (int ki = 0; ki < 2; ++ki){
      short8 af[4], bfr[4];
      #pragma unroll
      for (int mi = 0; mi < 4; mi++) af[mi]  = *(const short8*)&Al[wr*64 + mi*16 + c][ki*32 + g*8];
      #pragma unroll
      for (int ni = 0; ni < 4; ni++) bfr[ni] = *(const short8*)&Bl[wc*64 + ni*16 + c][ki*32 + g*8];
      #pragma unroll
      for (int mi = 0; mi < 4; mi++)
        #pragma unroll
        for (int ni = 0; ni < 4; ni++)
          acc[mi][ni] = mfma16(af[mi], bfr[ni], acc[mi][ni]);
    }
    __syncthreads();
  }

  if (mode == 2){
    int h = cy * 2 + wc;
    #pragma unroll
    for (int ni = 0; ni < 4; ni++){
      int col = C0 + wc*64 + ni*16 + c;
      int d = ni*16 + c;
      float bvv = bias[col];
      #pragma unroll
      for (int mi = 0; mi < 4; mi++){
        int row0 = R0 + wr*64 + mi*16 + g*4;
        int b = row0 >> 11, s0 = row0 & 2047;
        us4 pk;
        #pragma unroll
        for (int r = 0; r < 4; r++) pk[r] = f2bf(acc[mi][ni][r] + bvv);
        *(us4*)&outB[((size_t)(b*16 + h)*64 + d)*2048 + s0] = pk;
      }
    }
  } else {
    int h = cy * 2 + wc;
    const float qs = (mode == 0) ? 0.125f : 1.0f;
    float bvv[4];
    #pragma unroll
    for (int ni = 0; ni < 4; ni++) bvv[ni] = bias[C0 + wc*64 + ni*16 + c];
    #pragma unroll
    for (int mi = 0; mi < 4; mi++){
      int row0 = R0 + wr*64 + mi*16 + g*4;
      int b = row0 >> 11;
      #pragma unroll
      for (int r = 0; r < 4; r++){
        int s = (row0 + r) & 2047;
        float v0 = acc[mi][0][r] + bvv[0];
        float v1 = acc[mi][1][r] + bvv[1];
        float v2 = acc[mi][2][r] + bvv[2];
        float v3 = acc[mi][3][r] + bvv[3];
        float ca = cosT[s*32 + c],      sa = sinT[s*32 + c];
        float cb = cosT[s*32 + 16 + c], sb = sinT[s*32 + 16 + c];
        float o0 = (v0*ca - v2*sa) * qs, o2 = (v2*ca + v0*sa) * qs;
        float o1 = (v1*cb - v3*sb) * qs, o3 = (v3*cb + v1*sb) * qs;
        size_t base = ((size_t)(b*16 + h)*2048 + s)*64;
        outB[base +  0 + c] = f2bf(o0);
        outB[base + 16 + c] = f2bf(o1);
        outB[base + 32 + c] = f2bf(o2);
        outB[base + 48 + c] = f2bf(o3);
      }
    }
  }
}

// ---------------- output GEMM (AO x Wo^T + bo -> fp32 out) ----------------
__global__ __launch_bounds__(256, 2)
void out_gemm_k(const u16* __restrict__ A, const u16* __restrict__ BT,
                const float* __restrict__ bias, float* __restrict__ outF)
{
  __shared__ __align__(16) u16 Al[128][64];
  __shared__ __align__(16) u16 Bl[128][64];
  const int tid = threadIdx.x;
  const int w = tid >> 6, lane = tid & 63, g = lane >> 4, c = lane & 15;
  const int wr = w >> 1, wc = w & 1;
  const int R0 = blockIdx.x * 128, C0 = blockIdx.y * 128;

  f32x4 acc[4][4];
  const f32x4 vz = {0.f, 0.f, 0.f, 0.f};
  #pragma unroll
  for (int mi = 0; mi < 4; mi++)
    #pragma unroll
    for (int ni = 0; ni < 4; ni++) acc[mi][ni] = vz;

  const u16* gA[4]; const u16* gB[4]; u16* lA[4]; u16* lB[4];
  #pragma unroll
  for (int i = 0; i < 4; i++){
    int I = w * 4 + i;
    int rr = I * 8 + (lane >> 3), kk = (lane & 7) * 8;
    gA[i] = A  + (size_t)(R0 + rr) * 1024 + kk;
    gB[i] = BT + (size_t)(C0 + rr) * 1024 + kk;
    lA[i] = &Al[I * 8][0];
    lB[i] = &Bl[I * 8][0];
  }

  for (int t = 0; t < 16; ++t){
    const int k0 = t * 64;
    #pragma unroll
    for (int i = 0; i < 4; i++){
      gload16(gA[i] + k0, lA[i]);
      gload16(gB[i] + k0, lB[i]);
    }
    __syncthreads();
    #pragma unroll
    for (int ki = 0; ki < 2; ++ki){
      short8 af[4], bfr[4];
      #pragma unroll
      for (int mi = 0; mi < 4; mi++) af[mi]  = *(const short8*)&Al[wr*64 + mi*16 + c][ki*32 + g*8];
      #pragma unroll
      for (int ni = 0; ni < 4; ni++) bfr[ni] = *(const short8*)&Bl[wc*64 + ni*16 + c][ki*32 + g*8];
      #pragma unroll
      for (int mi = 0; mi < 4; mi++)
        #pragma unroll
        for (int ni = 0; ni < 4; ni++)
          acc[mi][ni] = mfma16(af[mi], bfr[ni], acc[mi][ni]);
    }
    __syncthreads();
  }

  #pragma unroll
  for (int mi = 0; mi < 4; mi++){
    #pragma unroll
    for (int ni = 0; ni < 4; ni++){
      int col = C0 + wc*64 + ni*16 + c;
      float bvv = bias[col];
      int row0 = R0 + wr*64 + mi*16 + g*4;
      #pragma unroll
      for (int r = 0; r < 4; r++)
        outF[(size_t)(row0 + r) * 1024 + col] = acc[mi][ni][r] + bvv;
    }
  }
}

// ---------------- flash attention (swapped-QK^T, zero-shuffle PV) ----------------
// Q,K: (b,h,s,d) bf16 (Q pre-scaled by 0.125).  V: (b,h,d,s) bf16.
// out AO: (b,s,h,d) bf16.  4 waves x 32 q-rows. KV tiles of 64, double-buffered.
// XCD swizzle: all 16 q-blocks of one bh land on the same XCD (K/V L2-local).
__global__ __launch_bounds__(256, 4)
void attn_fwd_k(const u16* __restrict__ Q, const u16* __restrict__ K, const u16* __restrict__ V,
                const int* __restrict__ msk, u16* __restrict__ AO)
{
  __shared__ __align__(16) u16 Kl[2][64][64];
  __shared__ __align__(16) u16 Vl[2][64][64];
  __shared__ int Ml[2048];
  const int tid = threadIdx.x;
  const int w = tid >> 6, lane = tid & 63, g = lane >> 4, c = lane & 15;

  // XCD-aware swizzle (bijective, 1024 = 8*128): XCD = lin%8 gets 8 full bh
  const int lin = blockIdx.y * 16 + blockIdx.x;
  const int v_  = (lin & 7) * 128 + (lin >> 3);
  const int bh = v_ >> 4, b = bh >> 4, h = bh & 15;
  const int qw = (v_ & 15) * 128 + w * 32;

  // per-lane staging sources (pre-swizzled cols; K rows pi-permuted)
  const int l3 = lane >> 3, l7 = lane & 7;
  const int scol = (l7 ^ l3) * 8;
  const u16* gK[2]; const u16* gV[2];
  #pragma unroll
  for (int i = 0; i < 2; i++){
    int s = (w*2 + i)*8 + l3;                                        // stored row
    int ps = (s & 0x20) | ((s & 0x10) >> 2) | ((s & 0x0C) << 1) | (s & 3); // pi(s)
    gK[i] = K + ((size_t)bh*2048 + ps)*64 + scol;
    gV[i] = V + ((size_t)bh*64 + s)*2048 + scol;
  }

  // stage mask row for this b (8KB) into LDS
  {
    const int* ms = msk + b*2048 + w*512 + lane*4;
    gload16(ms,       &Ml[w*512]);
    gload16(ms + 256, &Ml[w*512 + 256]);
  }
  // stage tile 0 into buf 0
  #pragma unroll
  for (int i = 0; i < 2; i++){
    gload16(gK[i], &Kl[0][(w*2+i)*8][0]);
    gload16(gV[i], &Vl[0][(w*2+i)*8][0]);
  }

  // Q B-fragments (row q = qw + mq*16 + c, k-slice ki*32 + g*8)
  short8 qb[2][2];
  #pragma unroll
  for (int mq = 0; mq < 2; mq++)
    #pragma unroll
    for (int ki = 0; ki < 2; ki++)
      qb[mq][ki] = *(const short8*)&Q[((size_t)bh*2048 + qw + mq*16 + c)*64 + ki*32 + g*8];

  f32x4 oacc[2][4];
  float mrun[2], lrun[2];
  const f32x4 vz = {0.f, 0.f, 0.f, 0.f};
  #pragma unroll
  for (int mq = 0; mq < 2; mq++){
    #pragma unroll
    for (int nd = 0; nd < 4; nd++) oacc[mq][nd] = vz;
    mrun[mq] = -1e30f; lrun[mq] = 0.f;
  }

  const int cs0 = (g*8) ^ ((c & 7) << 3);          // swizzled read col, ki=0
  const int cs1 = (32 + g*8) ^ ((c & 7) << 3);     // swizzled read col, ki=1

  for (int t = 0; t < 32; ++t){
    // stage tile t+1 into buf (t+1)&1  (t=31 over-stage is harmless, in-ws)
    {
      const size_t ko = (size_t)(t+1) * 64 * 64;   // u16: 64 rows ahead
      const size_t vo = (size_t)(t+1) * 64;        // u16: 64 cols ahead
      #pragma unroll
      for (int i = 0; i < 2; i++){
        gload16(gK[i] + ko, &Kl[(t+1)&1][(w*2+i)*8][0]);
        gload16(gV[i] + vo, &Vl[(t+1)&1][(w*2+i)*8][0]);
      }
    }
    asm volatile("s_waitcnt vmcnt(4)" ::: "memory");  // tile t drained; t+1 in flight
    __builtin_amdgcn_s_barrier();
    asm volatile("" ::: "memory");

    const u16* Kb = &Kl[t&1][0][0];
    const u16* Vb = &Vl[t&1][0][0];
    const int t0 = t * 64;

    // S^T = K (A) x Q (B): sacc[nt][mq] holds S[q=qw+mq*16+c][stored t = t0+nt*16+4g+r]
    f32x4 sacc[4][2];
    #pragma unroll
    for (int nt = 0; nt < 4; nt++){ sacc[nt][0] = vz; sacc[nt][1] = vz; }
    #pragma unroll
    for (int ki = 0; ki < 2; ki++){
      const int cs = ki ? cs1 : cs0;
      short8 ka[4];
      #pragma unroll
      for (int nt = 0; nt < 4; nt++) ka[nt] = *(const short8*)&Kb[(nt*16 + c)*64 + cs];
      #pragma unroll
      for (int nt = 0; nt < 4; nt++)
        #pragma unroll
        for (int mq = 0; mq < 2; mq++)
          sacc[nt][mq] = mfma16(ka[nt], qb[mq][ki], sacc[nt][mq]);
    }

    // mask: logical t of (nt,g,r) = t0 + 32*(nt>>1) + 8g + 4*(nt&1) + r
    i32x4 mv[4];
    #pragma unroll
    for (int nt = 0; nt < 4; nt++)
      mv[nt] = *(const i32x4*)&Ml[t0 + 32*(nt>>1) + 8*g + 4*(nt&1)];
    int ma = (mv[0][0] & mv[0][1]) & (mv[0][2] & mv[0][3]);
    ma &= (mv[1][0] & mv[1][1]) & (mv[1][2] & mv[1][3]);
    ma &= (mv[2][0] & mv[2][1]) & (mv[2][2] & mv[2][3]);
    ma &= (mv[3][0] & mv[3][1]) & (mv[3][2] & mv[3][3]);
    if (!__all(ma != 0)){
      #pragma unroll
      for (int nt = 0; nt < 4; nt++)
        #pragma unroll
        for (int r = 0; r < 4; r++){
          if (mv[nt][r] == 0){ sacc[nt][0][r] = -1e9f; sacc[nt][1][r] = -1e9f; }
        }
    }

    // online softmax, per lane for q = qw + mq*16 + c  (manual RTNE P-pack)
    float al[2];
    short8 pa[2][2];
    #pragma unroll
    for (int mq = 0; mq < 2; mq++){
      float m16 = sacc[0][mq][0];
      #pragma unroll
      for (int nt = 0; nt < 4; nt++)
        #pragma unroll
        for (int r = 0; r < 4; r++)
          m16 = fmaxf(m16, sacc[nt][mq][r]);
      m16 = fmaxf(m16, __shfl_xor(m16, 16, 64));
      m16 = fmaxf(m16, __shfl_xor(m16, 32, 64));
      float mn = fmaxf(mrun[mq], m16);
      al[mq] = exp2f((mrun[mq] - mn) * LOG2E);
      mrun[mq] = mn;
      const float nm = -mn * LOG2E;
      u32 prB[4][4];                     // rounded p as f32 bits (low16 = 0)
      float sum = 0.f;
      #pragma unroll
      for (int nt = 0; nt < 4; nt++)
        #pragma unroll
        for (int r = 0; r < 4; r++){
          float p = exp2f(fmaf(sacc[nt][mq][r], LOG2E, nm));
          u32 pb = (u32)f2bf(p) << 16;   // RTNE bf16, back as f32 bits
          prB[nt][r] = pb;
          sum += __builtin_bit_cast(float, pb);   // denominator == Σ rounded p
        }
      sum += __shfl_xor(sum, 16, 64);
      sum += __shfl_xor(sum, 32, 64);
      lrun[mq] = lrun[mq] * al[mq] + sum;
      #pragma unroll
      for (int ki = 0; ki < 2; ki++){
        u32x4 pk;
        pk[0] = (prB[2*ki  ][0] >> 16) | prB[2*ki  ][1];
        pk[1] = (prB[2*ki  ][2] >> 16) | prB[2*ki  ][3];
        pk[2] = (prB[2*ki+1][0] >> 16) | prB[2*ki+1][1];
        pk[3] = (prB[2*ki+1][2] >> 16) | prB[2*ki+1][3];
        pa[mq][ki] = __builtin_bit_cast(short8, pk);
      }
    }

    // rescale O by alpha (redistribute: O rows are q = 4g+r, alpha lives at q=c)
    #pragma unroll
    for (int mq = 0; mq < 2; mq++){
      float a0 = __shfl(al[mq], g*4 + 0, 64);
      float a1 = __shfl(al[mq], g*4 + 1, 64);
      float a2 = __shfl(al[mq], g*4 + 2, 64);
      float a3 = __shfl(al[mq], g*4 + 3, 64);
      #pragma unroll
      for (int nd = 0; nd < 4; nd++){
        oacc[mq][nd][0] *= a0; oacc[mq][nd][1] *= a1;
        oacc[mq][nd][2] *= a2; oacc[mq][nd][3] *= a3;
      }
    }

    // O += P (A) x V (B)
    #pragma unroll
    for (int ki = 0; ki < 2; ki++){
      const int cs = ki ? cs1 : cs0;
      short8 va[4];
      #pragma unroll
      for (int nd = 0; nd < 4; nd++) va[nd] = *(const short8*)&Vb[(nd*16 + c)*64 + cs];
      #pragma unroll
      for (int mq = 0; mq < 2; mq++)
        #pragma unroll
        for (int nd = 0; nd < 4; nd++)
          oacc[mq][nd] = mfma16(pa[mq][ki], va[nd], oacc[mq][nd]);
    }

    asm volatile("" ::: "memory");
    __builtin_amdgcn_s_barrier();
    asm volatile("" ::: "memory");
  }

  // epilogue: O rows q = qw + mq*16 + 4g + r; l lives at q=c lanes -> shfl
  #pragma unroll
  for (int mq = 0; mq < 2; mq++){
    #pragma unroll
    for (int r = 0; r < 4; r++){
      float li = __shfl(lrun[mq], g*4 + r, 64);
      float inv = 1.0f / li;
      int q = qw + mq*16 + g*4 + r;
      size_t base = ((size_t)b*2048 + q)*1024 + h*64;
      #pragma unroll
      for (int nd = 0; nd < 4; nd++)
        AO[base + nd*16 + c] = f2bf(oacc[mq][nd][r] * inv);
    }
  }
}

extern "C" void kernel_launch(void* const* d_in, const int* in_sizes, int n_in,
                              void* d_out, int out_size, void* d_ws, size_t ws_size,
                              hipStream_t stream)
{
  const float* x  = (const float*)d_in[0];
  const int* mask = (const int*)d_in[1];
  const float* Wq = (const float*)d_in[2];
  const float* bq = (const float*)d_in[3];
  const float* Wk = (const float*)d_in[4];
  const float* bk = (const float*)d_in[5];
  const float* Wv = (const float*)d_in[6];
  const float* bv = (const float*)d_in[7];
  const float* Wo = (const float*)d_in[8];
  const float* bo = (const float*)d_in[9];
  float* out = (float*)d_out;
  (void)in_sizes; (void)n_in; (void)out_size; (void)ws_size;

  char* ws = (char*)d_ws;
  size_t off = 0;
  auto alloc = [&](size_t bytes){ void* p = ws + off; off += (bytes + 255) & ~(size_t)255; return p; };
  u16* xb    = (u16*)alloc((size_t)8192 * 1024 * 2);
  u16* WT    = (u16*)alloc((size_t)4 * 1024 * 1024 * 2);
  float* cosT = (float*)alloc((size_t)2048 * 32 * 4);
  float* sinT = (float*)alloc((size_t)2048 * 32 * 4);
  u16* Qr    = (u16*)alloc((size_t)8192 * 1024 * 2);
  u16* Kr    = (u16*)alloc((size_t)8192 * 1024 * 2);
  u16* Vt    = (u16*)alloc((size_t)8192 * 1024 * 2);
  u16* AO    = (u16*)alloc((size_t)8192 * 1024 * 2);

  rope_tab_k<<<dim3(256), dim3(256), 0, stream>>>(cosT, sinT);
  cvt_x_k<<<dim3(8192), dim3(256), 0, stream>>>(x, xb, 8192 * 1024);
  wt_cvt_k<<<dim3(32, 32, 4), dim3(32, 8), 0, stream>>>(Wq, Wk, Wv, Wo, WT);

  qkv_gemm_k<<<dim3(64, 24), dim3(256), 0, stream>>>(xb, WT, bq, bk, bv, cosT, sinT, Qr, Kr, Vt);

  attn_fwd_k<<<dim3(16, 64), dim3(256), 0, stream>>>(Qr, Kr, Vt, mask, AO);

  out_gemm_k<<<dim3(64, 8), dim3(256), 0, stream>>>(AO, WT + 3*1024*1024, bo, out);
}

// Round 7
// 262.688 us; speedup vs baseline: 1.5791x; 1.0057x over previous
//
#include <hip/hip_runtime.h>
#include <math.h>

typedef __attribute__((ext_vector_type(8))) short short8;
typedef __attribute__((ext_vector_type(4))) float f32x4;
typedef __attribute__((ext_vector_type(4))) unsigned short us4;
typedef __attribute__((ext_vector_type(4))) unsigned int u32x4;
typedef __attribute__((ext_vector_type(4))) int i32x4;
typedef unsigned short u16;
typedef unsigned int u32;

#define LOG2E 1.4426950408889634f
// B=4, S=2048, E=1024, H=16, D=64, M=B*S=8192

static __device__ __forceinline__ u16 f2bf(float f){
  u32 u = __builtin_bit_cast(u32, f);
  u = (u + 0x7FFFu + ((u >> 16) & 1u)) >> 16;   // RTNE
  return (u16)u;
}
// NOTE: v_cvt_pk_bf16_f32 (and __float22bfloat162_rn) is NOT RTNE on gfx950 —
// using it for the P-pack cost 7e-3 absmax (rounds 2 & 5). Keep manual RTNE.

static __device__ __forceinline__ void gload16(const void* g, void* l){
  __builtin_amdgcn_global_load_lds((const __attribute__((address_space(1))) void*)g,
                                   (__attribute__((address_space(3))) void*)l,
                                   16, 0, 0);
}

static __device__ __forceinline__ f32x4 mfma16(short8 a, short8 b, f32x4 c){
  return __builtin_amdgcn_mfma_f32_16x16x32_bf16(a, b, c, 0, 0, 0);
}

// ---------------- RoPE cos/sin table: [s][i], i = 0..31 ----------------
__global__ void rope_tab_k(float* __restrict__ cosT, float* __restrict__ sinT){
  int idx = blockIdx.x * 256 + threadIdx.x;   // 2048*32 = 65536
  int s = idx >> 5, i = idx & 31;
  double th = pow(10000.0, -((double)(2 * i)) / 64.0);
  float ang = (float)s * (float)th;           // fp32 rounding matches reference
  cosT[idx] = (float)cos((double)ang);
  sinT[idx] = (float)sin((double)ang);
}

// ---------------- x fp32 -> bf16 ----------------
__global__ void cvt_x_k(const float* __restrict__ x, u16* __restrict__ xb, int n){
  int i = (blockIdx.x * 256 + threadIdx.x) * 4;
  if (i >= n) return;
  f32x4 v = *(const f32x4*)(x + i);
  us4 o; o[0]=f2bf(v[0]); o[1]=f2bf(v[1]); o[2]=f2bf(v[2]); o[3]=f2bf(v[3]);
  *(us4*)(xb + i) = o;
}

// ---------------- W (k,n) fp32 -> WT (n,k) bf16, 4 matrices ----------------
__global__ void wt_cvt_k(const float* __restrict__ W0, const float* __restrict__ W1,
                         const float* __restrict__ W2, const float* __restrict__ W3,
                         u16* __restrict__ out){
  __shared__ float t[32][33];
  const float* W = (blockIdx.z == 0) ? W0 : (blockIdx.z == 1) ? W1 : (blockIdx.z == 2) ? W2 : W3;
  u16* O = out + (size_t)blockIdx.z * 1024 * 1024;
  int tx = threadIdx.x, ty = threadIdx.y;
  int kb = blockIdx.y * 32, nb = blockIdx.x * 32;
  #pragma unroll
  for (int i = 0; i < 4; i++)
    t[ty + i*8][tx] = W[(size_t)(kb + ty + i*8) * 1024 + nb + tx];
  __syncthreads();
  #pragma unroll
  for (int i = 0; i < 4; i++)
    O[(size_t)(nb + ty + i*8) * 1024 + kb + tx] = f2bf(t[tx][ty + i*8]);
}

// ---------------- fused QKV GEMM 8192x1024x1024 bf16 MFMA ----------------
// grid (64, 24): mode = y>>3 (0=Q,1=K,2=V), cy = y&7.
// mode 0: bias+rope+0.125 -> Qr (b,h,s,d);  mode 1: bias+rope -> Kr (b,h,s,d)
// mode 2: bias -> Vt (b,h,d,s)
__global__ __launch_bounds__(256, 2)
void qkv_gemm_k(const u16* __restrict__ A, const u16* __restrict__ WT,
                const float* __restrict__ bq, const float* __restrict__ bk,
                const float* __restrict__ bv,
                const float* __restrict__ cosT, const float* __restrict__ sinT,
                u16* __restrict__ Qr, u16* __restrict__ Kr, u16* __restrict__ Vt)
{
  __shared__ __align__(16) u16 Al[128][64];
  __shared__ __align__(16) u16 Bl[128][64];
  const int mode = blockIdx.y >> 3;
  const int cy   = blockIdx.y & 7;
  const u16* BT = WT + (size_t)mode * 1024 * 1024;
  const float* bias = (mode == 0) ? bq : (mode == 1) ? bk : bv;
  u16* outB = (mode == 0) ? Qr : (mode == 1) ? Kr : Vt;

  const int tid = threadIdx.x;
  const int w = tid >> 6, lane = tid & 63, g = lane >> 4, c = lane & 15;
  const int wr = w >> 1, wc = w & 1;
  const int R0 = blockIdx.x * 128, C0 = cy * 128;

  f32x4 acc[4][4];
  const f32x4 vz = {0.f, 0.f, 0.f, 0.f};
  #pragma unroll
  for (int mi = 0; mi < 4; mi++)
    #pragma unroll
    for (int ni = 0; ni < 4; ni++) acc[mi][ni] = vz;

  const u16* gA[4]; const u16* gB[4]; u16* lA[4]; u16* lB[4];
  #pragma unroll
  for (int i = 0; i < 4; i++){
    int I = w * 4 + i;
    int rr = I * 8 + (lane >> 3), kk = (lane & 7) * 8;
    gA[i] = A  + (size_t)(R0 + rr) * 1024 + kk;
    gB[i] = BT + (size_t)(C0 + rr) * 1024 + kk;
    lA[i] = &Al[I * 8][0];
    lB[i] = &Bl[I * 8][0];
  }

  for (int t = 0; t < 16; ++t){
    const int k0 = t * 64;
    #pragma unroll
    for (int i = 0; i < 4; i++){
      gload16(gA[i] + k0, lA[i]);
      gload16(gB[i] + k0, lB[i]);
    }
    __syncthreads();
    #pragma unroll
    for (int ki = 0; ki < 2; ++ki){
      short8 af[4], bfr[4];
      #pragma unroll
      for (int mi = 0; mi < 4; mi++) af[mi]  = *(const short8*)&Al[wr*64 + mi*16 + c][ki*32 + g*8];
      #pragma unroll
      for (int ni = 0; ni < 4; ni++) bfr[ni] = *(const short8*)&Bl[wc*64 + ni*16 + c][ki*32 + g*8];
      #pragma unroll
      for (int mi = 0; mi < 4; mi++)
        #pragma unroll
        for (int ni = 0; ni < 4; ni++)
          acc[mi][ni] = mfma16(af[mi], bfr[ni], acc[mi][ni]);
    }
    __syncthreads();
  }

  if (mode == 2){
    int h = cy * 2 + wc;
    #pragma unroll
    for (int ni = 0; ni < 4; ni++){
      int col = C0 + wc*64 + ni*16 + c;
      int d = ni*16 + c;
      float bvv = bias[col];
      #pragma unroll
      for (int mi = 0; mi < 4; mi++){
        int row0 = R0 + wr*64 + mi*16 + g*4;
        int b = row0 >> 11, s0 = row0 & 2047;
        us4 pk;
        #pragma unroll
        for (int r = 0; r < 4; r++) pk[r] = f2bf(acc[mi][ni][r] + bvv);
        *(us4*)&outB[((size_t)(b*16 + h)*64 + d)*2048 + s0] = pk;
      }
    }
  } else {
    int h = cy * 2 + wc;
    const float qs = (mode == 0) ? 0.125f : 1.0f;
    float bvv[4];
    #pragma unroll
    for (int ni = 0; ni < 4; ni++) bvv[ni] = bias[C0 + wc*64 + ni*16 + c];
    #pragma unroll
    for (int mi = 0; mi < 4; mi++){
      int row0 = R0 + wr*64 + mi*16 + g*4;
      int b = row0 >> 11;
      #pragma unroll
      for (int r = 0; r < 4; r++){
        int s = (row0 + r) & 2047;
        float v0 = acc[mi][0][r] + bvv[0];
        float v1 = acc[mi][1][r] + bvv[1];
        float v2 = acc[mi][2][r] + bvv[2];
        float v3 = acc[mi][3][r] + bvv[3];
        float ca = cosT[s*32 + c],      sa = sinT[s*32 + c];
        float cb = cosT[s*32 + 16 + c], sb = sinT[s*32 + 16 + c];
        float o0 = (v0*ca - v2*sa) * qs, o2 = (v2*ca + v0*sa) * qs;
        float o1 = (v1*cb - v3*sb) * qs, o3 = (v3*cb + v1*sb) * qs;
        size_t base = ((size_t)(b*16 + h)*2048 + s)*64;
        outB[base +  0 + c] = f2bf(o0);
        outB[base + 16 + c] = f2bf(o1);
        outB[base + 32 + c] = f2bf(o2);
        outB[base + 48 + c] = f2bf(o3);
      }
    }
  }
}

// ---------------- output GEMM (AO x Wo^T + bo -> fp32 out) ----------------
__global__ __launch_bounds__(256, 2)
void out_gemm_k(const u16* __restrict__ A, const u16* __restrict__ BT,
                const float* __restrict__ bias, float* __restrict__ outF)
{
  __shared__ __align__(16) u16 Al[128][64];
  __shared__ __align__(16) u16 Bl[128][64];
  const int tid = threadIdx.x;
  const int w = tid >> 6, lane = tid & 63, g = lane >> 4, c = lane & 15;
  const int wr = w >> 1, wc = w & 1;
  const int R0 = blockIdx.x * 128, C0 = blockIdx.y * 128;

  f32x4 acc[4][4];
  const f32x4 vz = {0.f, 0.f, 0.f, 0.f};
  #pragma unroll
  for (int mi = 0; mi < 4; mi++)
    #pragma unroll
    for (int ni = 0; ni < 4; ni++) acc[mi][ni] = vz;

  const u16* gA[4]; const u16* gB[4]; u16* lA[4]; u16* lB[4];
  #pragma unroll
  for (int i = 0; i < 4; i++){
    int I = w * 4 + i;
    int rr = I * 8 + (lane >> 3), kk = (lane & 7) * 8;
    gA[i] = A  + (size_t)(R0 + rr) * 1024 + kk;
    gB[i] = BT + (size_t)(C0 + rr) * 1024 + kk;
    lA[i] = &Al[I * 8][0];
    lB[i] = &Bl[I * 8][0];
  }

  for (int t = 0; t < 16; ++t){
    const int k0 = t * 64;
    #pragma unroll
    for (int i = 0; i < 4; i++){
      gload16(gA[i] + k0, lA[i]);
      gload16(gB[i] + k0, lB[i]);
    }
    __syncthreads();
    #pragma unroll
    for (int ki = 0; ki < 2; ++ki){
      short8 af[4], bfr[4];
      #pragma unroll
      for (int mi = 0; mi < 4; mi++) af[mi]  = *(const short8*)&Al[wr*64 + mi*16 + c][ki*32 + g*8];
      #pragma unroll
      for (int ni = 0; ni < 4; ni++) bfr[ni] = *(const short8*)&Bl[wc*64 + ni*16 + c][ki*32 + g*8];
      #pragma unroll
      for (int mi = 0; mi < 4; mi++)
        #pragma unroll
        for (int ni = 0; ni < 4; ni++)
          acc[mi][ni] = mfma16(af[mi], bfr[ni], acc[mi][ni]);
    }
    __syncthreads();
  }

  #pragma unroll
  for (int mi = 0; mi < 4; mi++){
    #pragma unroll
    for (int ni = 0; ni < 4; ni++){
      int col = C0 + wc*64 + ni*16 + c;
      float bvv = bias[col];
      int row0 = R0 + wr*64 + mi*16 + g*4;
      #pragma unroll
      for (int r = 0; r < 4; r++)
        outF[(size_t)(row0 + r) * 1024 + col] = acc[mi][ni][r] + bvv;
    }
  }
}

// ---------------- flash attention (swapped-QK^T, zero-shuffle PV) ----------------
// Q,K: (b,h,s,d) bf16 (Q pre-scaled by 0.125).  V: (b,h,d,s) bf16.
// out AO: (b,s,h,d) bf16.  4 waves x 32 q-rows. KV tiles of 64, double-buffered.
// XCD swizzle: all 16 q-blocks of one bh land on the same XCD (K/V L2-local).
// Softmax: tree max/sum (short dep chains), defer-max (THR=8), perm-packed
// manual-RTNE P (sum over unrounded p — round-1-proven numerics).
__global__ __launch_bounds__(256, 4)
void attn_fwd_k(const u16* __restrict__ Q, const u16* __restrict__ K, const u16* __restrict__ V,
                const int* __restrict__ msk, u16* __restrict__ AO)
{
  __shared__ __align__(16) u16 Kl[2][64][64];
  __shared__ __align__(16) u16 Vl[2][64][64];
  __shared__ __align__(8) unsigned char Ml[2048];
  const int tid = threadIdx.x;
  const int w = tid >> 6, lane = tid & 63, g = lane >> 4, c = lane & 15;

  // XCD-aware swizzle (bijective, 1024 = 8*128): XCD = lin%8 gets 8 full bh
  const int lin = blockIdx.y * 16 + blockIdx.x;
  const int v_  = (lin & 7) * 128 + (lin >> 3);
  const int bh = v_ >> 4, b = bh >> 4, h = bh & 15;
  const int qw = (v_ & 15) * 128 + w * 32;

  // pack mask row for this b into LDS as u8 (0/1)
  {
    const int* mp = msk + b*2048 + tid*8;
    i32x4 a = *(const i32x4*)mp;
    i32x4 d2 = *(const i32x4*)(mp + 4);
    u32 lo = (a[0]  ? 1u : 0u) | (a[1]  ? 0x100u : 0u) | (a[2]  ? 0x10000u : 0u) | (a[3]  ? 0x1000000u : 0u);
    u32 hi = (d2[0] ? 1u : 0u) | (d2[1] ? 0x100u : 0u) | (d2[2] ? 0x10000u : 0u) | (d2[3] ? 0x1000000u : 0u);
    *(u32*)&Ml[tid*8]     = lo;
    *(u32*)&Ml[tid*8 + 4] = hi;
  }
  asm volatile("s_waitcnt lgkmcnt(0)" ::: "memory");  // Ml writes drained before first barrier

  // Q B-fragments (row q = qw + mq*16 + c, k-slice ki*32 + g*8)
  short8 qb[2][2];
  #pragma unroll
  for (int mq = 0; mq < 2; mq++)
    #pragma unroll
    for (int ki = 0; ki < 2; ki++)
      qb[mq][ki] = *(const short8*)&Q[((size_t)bh*2048 + qw + mq*16 + c)*64 + ki*32 + g*8];

  // per-lane staging sources (pre-swizzled cols; K rows pi-permuted)
  const int l3 = lane >> 3, l7 = lane & 7;
  const int scol = (l7 ^ l3) * 8;
  const u16* gK[2]; const u16* gV[2];
  #pragma unroll
  for (int i = 0; i < 2; i++){
    int s = (w*2 + i)*8 + l3;                                        // stored row
    int ps = (s & 0x20) | ((s & 0x10) >> 2) | ((s & 0x0C) << 1) | (s & 3); // pi(s)
    gK[i] = K + ((size_t)bh*2048 + ps)*64 + scol;
    gV[i] = V + ((size_t)bh*64 + s)*2048 + scol;
  }
  // stage tile 0 into buf 0
  #pragma unroll
  for (int i = 0; i < 2; i++){
    gload16(gK[i], &Kl[0][(w*2+i)*8][0]);
    gload16(gV[i], &Vl[0][(w*2+i)*8][0]);
  }

  f32x4 oacc[2][4];
  float mrun[2], lrun[2];
  const f32x4 vz = {0.f, 0.f, 0.f, 0.f};
  #pragma unroll
  for (int mq = 0; mq < 2; mq++){
    #pragma unroll
    for (int nd = 0; nd < 4; nd++) oacc[mq][nd] = vz;
    mrun[mq] = -1e30f; lrun[mq] = 0.f;
  }

  const int cs0 = (g*8) ^ ((c & 7) << 3);          // swizzled read col, ki=0
  const int cs1 = (32 + g*8) ^ ((c & 7) << 3);     // swizzled read col, ki=1

  for (int t = 0; t < 32; ++t){
    // stage tile t+1 into buf (t+1)&1  (t=31 over-stage is harmless, in-ws)
    {
      const size_t ko = (size_t)(t+1) * 64 * 64;   // u16: 64 rows ahead
      const size_t vo = (size_t)(t+1) * 64;        // u16: 64 cols ahead
      #pragma unroll
      for (int i = 0; i < 2; i++){
        gload16(gK[i] + ko, &Kl[(t+1)&1][(w*2+i)*8][0]);
        gload16(gV[i] + vo, &Vl[(t+1)&1][(w*2+i)*8][0]);
      }
    }
    asm volatile("s_waitcnt vmcnt(4)" ::: "memory");  // tile t drained; t+1 in flight
    __builtin_amdgcn_s_barrier();
    asm volatile("" ::: "memory");

    const u16* Kb = &Kl[t&1][0][0];
    const u16* Vb = &Vl[t&1][0][0];
    const int t0 = t * 64;

    // S^T = K (A) x Q (B): sacc[nt][mq] holds S[q=qw+mq*16+c][stored t = t0+nt*16+4g+r]
    f32x4 sacc[4][2];
    #pragma unroll
    for (int nt = 0; nt < 4; nt++){ sacc[nt][0] = vz; sacc[nt][1] = vz; }
    #pragma unroll
    for (int ki = 0; ki < 2; ki++){
      const int cs = ki ? cs1 : cs0;
      short8 ka[4];
      #pragma unroll
      for (int nt = 0; nt < 4; nt++) ka[nt] = *(const short8*)&Kb[(nt*16 + c)*64 + cs];
      #pragma unroll
      for (int nt = 0; nt < 4; nt++)
        #pragma unroll
        for (int mq = 0; mq < 2; mq++)
          sacc[nt][mq] = mfma16(ka[nt], qb[mq][ki], sacc[nt][mq]);
    }

    // mask (u8): logical t of (nt,g,r) = t0 + 32*(nt>>1) + 8g + 4*(nt&1) + r
    {
      const u32 mw0 = *(const u32*)&Ml[t0 + 8*g];
      const u32 mw1 = *(const u32*)&Ml[t0 + 8*g + 4];
      const u32 mw2 = *(const u32*)&Ml[t0 + 32 + 8*g];
      const u32 mw3 = *(const u32*)&Ml[t0 + 32 + 8*g + 4];
      if (!__all((mw0 & mw1 & mw2 & mw3) == 0x01010101u)){
        const u32 mw[4] = {mw0, mw1, mw2, mw3};
        #pragma unroll
        for (int nt = 0; nt < 4; nt++)
          #pragma unroll
          for (int r = 0; r < 4; r++)
            if (((mw[nt] >> (8*r)) & 0xFFu) == 0){ sacc[nt][0][r] = -1e9f; sacc[nt][1][r] = -1e9f; }
      }
    }

    // tile max (tree), per lane for q = qw + mq*16 + c
    float pm[2];
    #pragma unroll
    for (int mq = 0; mq < 2; mq++){
      float a0 = fmaxf(fmaxf(sacc[0][mq][0], sacc[0][mq][1]), fmaxf(sacc[0][mq][2], sacc[0][mq][3]));
      float a1 = fmaxf(fmaxf(sacc[1][mq][0], sacc[1][mq][1]), fmaxf(sacc[1][mq][2], sacc[1][mq][3]));
      float a2 = fmaxf(fmaxf(sacc[2][mq][0], sacc[2][mq][1]), fmaxf(sacc[2][mq][2], sacc[2][mq][3]));
      float a3 = fmaxf(fmaxf(sacc[3][mq][0], sacc[3][mq][1]), fmaxf(sacc[3][mq][2], sacc[3][mq][3]));
      float mm = fmaxf(fmaxf(a0, a1), fmaxf(a2, a3));
      mm = fmaxf(mm, __shfl_xor(mm, 16, 64));
      mm = fmaxf(mm, __shfl_xor(mm, 32, 64));
      pm[mq] = mm;
    }

    // defer-max: rescale only when max grew by > 8 (skip is EXACT when pm<=mrun)
    if (__any((pm[0] > mrun[0] + 8.f) | (pm[1] > mrun[1] + 8.f))){
      float al[2];
      #pragma unroll
      for (int mq = 0; mq < 2; mq++){
        float mn = fmaxf(mrun[mq], pm[mq]);
        al[mq] = exp2f((mrun[mq] - mn) * LOG2E);
        mrun[mq] = mn;
        lrun[mq] *= al[mq];
      }
      #pragma unroll
      for (int mq = 0; mq < 2; mq++){
        float b0 = __shfl(al[mq], g*4 + 0, 64);
        float b1 = __shfl(al[mq], g*4 + 1, 64);
        float b2 = __shfl(al[mq], g*4 + 2, 64);
        float b3 = __shfl(al[mq], g*4 + 3, 64);
        #pragma unroll
        for (int nd = 0; nd < 4; nd++){
          oacc[mq][nd][0] *= b0; oacc[mq][nd][1] *= b1;
          oacc[mq][nd][2] *= b2; oacc[mq][nd][3] *= b3;
        }
      }
    }

    // P = exp2((s - m)*log2e): RTNE-round for PV, tree-sum unrounded for l
    short8 pa[2][2];
    #pragma unroll
    for (int mq = 0; mq < 2; mq++){
      const float nm = -mrun[mq] * LOG2E;
      float p[16]; u32 rb[16];
      #pragma unroll
      for (int nt = 0; nt < 4; nt++)
        #pragma unroll
        for (int r = 0; r < 4; r++){
          float pp = exp2f(fmaf(sacc[nt][mq][r], LOG2E, nm));
          p[nt*4 + r] = pp;
          u32 u = __builtin_bit_cast(u32, pp);
          rb[nt*4 + r] = u + 0x7FFFu + ((u >> 16) & 1u);   // RTNE in bytes 2,3
        }
      float s0 = (p[0] + p[1]) + (p[2] + p[3]);
      float s1 = (p[4] + p[5]) + (p[6] + p[7]);
      float s2 = (p[8] + p[9]) + (p[10] + p[11]);
      float s3 = (p[12] + p[13]) + (p[14] + p[15]);
      float sum = (s0 + s1) + (s2 + s3);
      sum += __shfl_xor(sum, 16, 64);
      sum += __shfl_xor(sum, 32, 64);
      lrun[mq] += sum;
      u32x4 q0 = { __builtin_amdgcn_perm(rb[1],  rb[0],  0x07060302u),
                   __builtin_amdgcn_perm(rb[3],  rb[2],  0x07060302u),
                   __builtin_amdgcn_perm(rb[5],  rb[4],  0x07060302u),
                   __builtin_amdgcn_perm(rb[7],  rb[6],  0x07060302u) };
      u32x4 q1 = { __builtin_amdgcn_perm(rb[9],  rb[8],  0x07060302u),
                   __builtin_amdgcn_perm(rb[11], rb[10], 0x07060302u),
                   __builtin_amdgcn_perm(rb[13], rb[12], 0x07060302u),
                   __builtin_amdgcn_perm(rb[15], rb[14], 0x07060302u) };
      pa[mq][0] = __builtin_bit_cast(short8, q0);
      pa[mq][1] = __builtin_bit_cast(short8, q1);
    }

    // O += P (A) x V (B)
    #pragma unroll
    for (int ki = 0; ki < 2; ki++){
      const int cs = ki ? cs1 : cs0;
      short8 va[4];
      #pragma unroll
      for (int nd = 0; nd < 4; nd++) va[nd] = *(const short8*)&Vb[(nd*16 + c)*64 + cs];
      #pragma unroll
      for (int mq = 0; mq < 2; mq++)
        #pragma unroll
        for (int nd = 0; nd < 4; nd++)
          oacc[mq][nd] = mfma16(pa[mq][ki], va[nd], oacc[mq][nd]);
    }

    asm volatile("" ::: "memory");
    __builtin_amdgcn_s_barrier();
    asm volatile("" ::: "memory");
  }

  // epilogue: O rows q = qw + mq*16 + 4g + r; l lives at q=c lanes -> shfl
  #pragma unroll
  for (int mq = 0; mq < 2; mq++){
    #pragma unroll
    for (int r = 0; r < 4; r++){
      float li = __shfl(lrun[mq], g*4 + r, 64);
      float inv = 1.0f / li;
      int q = qw + mq*16 + g*4 + r;
      size_t base = ((size_t)b*2048 + q)*1024 + h*64;
      #pragma unroll
      for (int nd = 0; nd < 4; nd++)
        AO[base + nd*16 + c] = f2bf(oacc[mq][nd][r] * inv);
    }
  }
}

extern "C" void kernel_launch(void* const* d_in, const int* in_sizes, int n_in,
                              void* d_out, int out_size, void* d_ws, size_t ws_size,
                              hipStream_t stream)
{
  const float* x  = (const float*)d_in[0];
  const int* mask = (const int*)d_in[1];
  const float* Wq = (const float*)d_in[2];
  const float* bq = (const float*)d_in[3];
  const float* Wk = (const float*)d_in[4];
  const float* bk = (const float*)d_in[5];
  const float* Wv = (const float*)d_in[6];
  const float* bv = (const float*)d_in[7];
  const float* Wo = (const float*)d_in[8];
  const float* bo = (const float*)d_in[9];
  float* out = (float*)d_out;
  (void)in_sizes; (void)n_in; (void)out_size; (void)ws_size;

  char* ws = (char*)d_ws;
  size_t off = 0;
  auto alloc = [&](size_t bytes){ void* p = ws + off; off += (bytes + 255) & ~(size_t)255; return p; };
  u16* xb    = (u16*)alloc((size_t)8192 * 1024 * 2);
  u16* WT    = (u16*)alloc((size_t)4 * 1024 * 1024 * 2);
  float* cosT = (float*)alloc((size_t)2048 * 32 * 4);
  float* sinT = (float*)alloc((size_t)2048 * 32 * 4);
  u16* Qr    = (u16*)alloc((size_t)8192 * 1024 * 2);
  u16* Kr    = (u16*)alloc((size_t)8192 * 1024 * 2);
  u16* Vt    = (u16*)alloc((size_t)8192 * 1024 * 2);
  u16* AO    = (u16*)alloc((size_t)8192 * 1024 * 2);

  rope_tab_k<<<dim3(256), dim3(256), 0, stream>>>(cosT, sinT);
  cvt_x_k<<<dim3(8192), dim3(256), 0, stream>>>(x, xb, 8192 * 1024);
  wt_cvt_k<<<dim3(32, 32, 4), dim3(32, 8), 0, stream>>>(Wq, Wk, Wv, Wo, WT);

  qkv_gemm_k<<<dim3(64, 24), dim3(256), 0, stream>>>(xb, WT, bq, bk, bv, cosT, sinT, Qr, Kr, Vt);

  attn_fwd_k<<<dim3(16, 64), dim3(256), 0, stream>>>(Qr, Kr, Vt, mask, AO);

  out_gemm_k<<<dim3(64, 8), dim3(256), 0, stream>>>(AO, WT + 3*1024*1024, bo, out);
}